// Round 2
// baseline (90.357 us; speedup 1.0000x reference)
//
#include <hip/hip_runtime.h>
#include <hip/hip_bf16.h>
#include <math.h>

typedef unsigned long long u64;
typedef unsigned int u32;

#define N 4096
#define NW 64          // 64-bit words per 4096-bit row
#define ROWLEN 85

// ---------------------------------------------------------------------------
// K1: decode — one wave (64 lanes) per prediction row.
//   lanes 0..63 hold class logits 0..63; lanes 0..15 also hold 64..79.
//   shfl-butterfly reductions for max / sumexp / argmax (first-index ties).
//   Writes: out rows [x1,y1,x2,y2,score] (unmasked), labels-as-float section,
//           labels_i (int scratch), zeroes rank_of for K2's atomics.
// ---------------------------------------------------------------------------
__global__ __launch_bounds__(256) void k_decode(const float* __restrict__ pred,
    float* __restrict__ out, int* __restrict__ labels_i, int* __restrict__ rank_of) {
  int lane = threadIdx.x & 63;
  int r = (blockIdx.x << 2) + (threadIdx.x >> 6);
  const float* p = pred + r * ROWLEN;
  float conf = p[0];
  float c1 = p[1 + lane];
  float c2 = (lane < 16) ? p[65 + lane] : -INFINITY;
  float b0 = p[81], b1 = p[82], b2 = p[83], b3 = p[84];

  float m = fmaxf(c1, c2);
  for (int off = 32; off; off >>= 1) m = fmaxf(m, __shfl_xor(m, off));
  float s = expf(c1 - m) + expf(c2 - m);          // expf(-inf)=0 for lane>=16
  for (int off = 32; off; off >>= 1) s += __shfl_xor(s, off);

  float av = c1; int ai = lane;
  if (c2 > av) { av = c2; ai = 64 + lane; }
  for (int off = 32; off; off >>= 1) {
    float ov = __shfl_xor(av, off); int oi = __shfl_xor(ai, off);
    if (ov > av || (ov == av && oi < ai)) { av = ov; ai = oi; }
  }

  if (lane == 0) {
    float sig = 1.0f / (1.0f + expf(-conf));
    float score = sig * (1.0f / s);               // sig * softmax_max, matches ref op order
    float gx = (float)(r >> 6), gy = (float)(r & 63);
    float cx = (1.0f / (1.0f + expf(-b0)) + gx) * 32.0f;
    float cy = (1.0f / (1.0f + expf(-b1)) + gy) * 32.0f;
    float wx = expf(b2), wy = expf(b3);
    const float inv = 1.0f / 2048.0f;
    float x1 = fminf(fmaxf((cx - wx) * inv, 0.0f), 1.0f);
    float y1 = fminf(fmaxf((cy - wy) * inv, 0.0f), 1.0f);
    float x2 = fminf(fmaxf((cx + wx) * inv, 0.0f), 1.0f);
    float y2 = fminf(fmaxf((cy + wy) * inv, 0.0f), 1.0f);
    out[r*5+0] = x1; out[r*5+1] = y1; out[r*5+2] = x2; out[r*5+3] = y2;
    out[r*5+4] = score;
    out[N*5 + r] = (float)ai;                     // labels output (as float)
    labels_i[r] = ai;
    rank_of[r] = 0;
  }
}

// ---------------------------------------------------------------------------
// K2: stable-descending rank, j-sliced. key = valid ? score : -1 (sentinel).
//   rank_i = #{j : k_j > k_i  or  (k_j == k_i and j < i)}   (== stable argsort)
// ---------------------------------------------------------------------------
__global__ __launch_bounds__(256) void k_rank(const float* __restrict__ out,
                                              int* __restrict__ rank_of) {
  __shared__ float kj[256];
  int i  = (blockIdx.x << 8) + threadIdx.x;
  int j0 = blockIdx.y << 8;
  {
    float sc = out[(j0 + threadIdx.x) * 5 + 4];
    kj[threadIdx.x] = (sc > 0.01f) ? sc : -1.0f;
  }
  __syncthreads();
  float sci = out[i*5+4];
  float ki = (sci > 0.01f) ? sci : -1.0f;
  int rnk = 0;
  #pragma unroll 8
  for (int jj = 0; jj < 256; ++jj) {
    float v = kj[jj];
    rnk += (v > ki || (v == ki && (j0 + jj) < i)) ? 1 : 0;
  }
  if (rnk) atomicAdd(&rank_of[i], rnk);
}

__global__ __launch_bounds__(256) void k_scatter(const int* __restrict__ rank_of,
                                                 int* __restrict__ order) {
  int i = (blockIdx.x << 8) + threadIdx.x;
  order[rank_of[i]] = i;                           // rank_of is a permutation
}

// ---------------------------------------------------------------------------
// K2b: gather candidate data into rank order + per-64 valid bitmask.
// ---------------------------------------------------------------------------
__global__ __launch_bounds__(256) void k_gather(const float* __restrict__ out,
    const int* __restrict__ labels_i, const int* __restrict__ order,
    float4* __restrict__ rbox, int* __restrict__ rlabel, u64* __restrict__ rvalid) {
  int r = (blockIdx.x << 8) + threadIdx.x;
  int idx = order[r];
  float x1 = out[idx*5+0], y1 = out[idx*5+1], x2 = out[idx*5+2], y2 = out[idx*5+3];
  float sc = out[idx*5+4];
  rbox[r] = make_float4(x1, y1, x2, y2);
  rlabel[r] = labels_i[idx];
  u64 bal = __ballot(sc > 0.01f);
  if ((threadIdx.x & 63) == 0) rvalid[r >> 6] = bal;
}

// ---------------------------------------------------------------------------
// K3: suppression bit-matrix in rank space (mat[r] bit s: r suppresses s),
//   + per-(row, s-half) nonzero flags. grid (2 s-tiles, 256 row-chunks of 16).
//   s-tile of 2048 candidates staged in LDS (40KB). One ballot per (row,word).
// ---------------------------------------------------------------------------
__global__ __launch_bounds__(256) void k_mat(const float4* __restrict__ rbox,
    const int* __restrict__ rlabel, u64* __restrict__ mat, u32* __restrict__ flag2) {
  __shared__ float4 sbox[2048];
  __shared__ int slab[2048];
  int t = blockIdx.x;                // s-tile 0..1
  int base = t << 11;
  for (int k = threadIdx.x; k < 2048; k += 256) {
    sbox[k] = rbox[base + k];
    slab[k] = rlabel[base + k];
  }
  __syncthreads();
  int lane = threadIdx.x & 63;
  int r0 = (blockIdx.y << 4) + ((threadIdx.x >> 6) << 2);
  for (int q = 0; q < 4; ++q) {
    int r = r0 + q;
    float4 br = rbox[r];
    int lr = rlabel[r];
    float ar = (br.w - br.y) * (br.z - br.x);
    u64 myw = 0; u32 any = 0;
    for (int w = 0; w < 32; ++w) {
      int sl = (w << 6) + lane;
      float4 bs = sbox[sl];
      int ls = slab[sl];
      float as = (bs.w - bs.y) * (bs.z - bs.x);
      float xx1 = fmaxf(br.x, bs.x);
      float yy1 = fmaxf(br.y, bs.y);
      float xx2 = fminf(br.z, bs.z);
      float yy2 = fminf(br.w, bs.w);
      float inter = fmaxf(xx2 - xx1, 0.0f) * fmaxf(yy2 - yy1, 0.0f);
      float uni = ar + as - inter;                 // a_r + a_s - inter (>0 always)
      float iou = inter / uni;                     // exact ref formula incl. division
      int sg = base + sl;
      bool sup = (ls == lr) && (iou > 0.5f) && (sg != r);
      u64 bal = __ballot(sup);
      any |= (u32)(bal != 0ull);
      if (lane == w) myw = bal;                    // lane w keeps word w (w<32)
    }
    if (lane < 32) mat[(size_t)r * NW + (t << 5) + lane] = myw;
    if (lane == 0) flag2[(t << 12) + r] = any;
  }
}

// ---------------------------------------------------------------------------
// K4: sequential greedy NMS, single wave. supp/valid/kept bitmasks: lane l
//   owns ranks [64l, 64l+64). Per 64-rank block:
//     - fast path: no intra-block edges among active -> keep all active
//     - inter suppression rows OR-ed only for kept candidates with flag set
// ---------------------------------------------------------------------------
__global__ __launch_bounds__(64) void k_greedy(const u64* __restrict__ mat,
    const u64* __restrict__ rvalid, const u32* __restrict__ flag2,
    u64* __restrict__ keptmask) {
  int lane = threadIdx.x;
  u64 valid = rvalid[lane];
  u64 supp = 0, kept = 0;
  for (int b = 0; b < 64; ++b) {
    u64 intra = mat[(size_t)((b << 6) + lane) * NW + b];   // diag-block column word
    u32 f = flag2[(b << 6) + lane] | flag2[4096 + (b << 6) + lane];
    u64 flagw = __ballot(f != 0);
    u64 sb = __shfl(supp, b);
    u64 vb = __shfl(valid, b);
    u64 act = vb & ~sb;
    u64 res = act;
    u64 anyintra = __ballot(intra != 0ull);
    if (anyintra & act) {                          // rare: serial in-block resolve
      u64 rem = act; res = 0;
      while (rem) {
        int pp = (int)__ffsll(rem) - 1;
        rem &= rem - 1;
        res |= 1ull << pp;
        u64 rowp = __shfl(intra, pp);
        rem &= ~rowp;
      }
    }
    if (lane == b) kept = res;
    u64 need = res & flagw;                        // rare: rows with any edge
    while (need) {
      int pp = (int)__ffsll(need) - 1;
      need &= need - 1;
      supp |= mat[(size_t)((b << 6) + pp) * NW + lane];
    }
  }
  keptmask[lane] = kept;
}

// ---------------------------------------------------------------------------
// K5: mask out rows by keep, emit keep section as floats.
// ---------------------------------------------------------------------------
__global__ __launch_bounds__(256) void k_final(float* __restrict__ out,
    const int* __restrict__ rank_of, const u64* __restrict__ keptmask) {
  int i = (blockIdx.x << 8) + threadIdx.x;
  int r = rank_of[i];
  float k = (float)((keptmask[r >> 6] >> (r & 63)) & 1ull);
  out[i*5+0] *= k; out[i*5+1] *= k; out[i*5+2] *= k; out[i*5+3] *= k; out[i*5+4] *= k;
  out[N*5 + N + i] = k;
}

// ---------------------------------------------------------------------------
// ws layout (bytes):
//   0        mat       u64[4096*64]   2097152
//   2097152  order     i32[4096]
//   2113536  rank_of   i32[4096]
//   2129920  rbox      float4[4096]
//   2195456  rlabel    i32[4096]
//   2211840  rvalid    u64[64]
//   2212352  keptmask  u64[64]
//   2212864  labels_i  i32[4096]
//   2229248  flag2     u32[2*4096]
//   total 2262016 bytes
// ---------------------------------------------------------------------------
extern "C" void kernel_launch(void* const* d_in, const int* in_sizes, int n_in,
                              void* d_out, int out_size, void* d_ws, size_t ws_size,
                              hipStream_t stream) {
  const float* pred = (const float*)d_in[0];
  float* out = (float*)d_out;
  char* ws = (char*)d_ws;
  u64*    mat      = (u64*)(ws);
  int*    order    = (int*)(ws + 2097152);
  int*    rank_of  = (int*)(ws + 2113536);
  float4* rbox     = (float4*)(ws + 2129920);
  int*    rlabel   = (int*)(ws + 2195456);
  u64*    rvalid   = (u64*)(ws + 2211840);
  u64*    keptmask = (u64*)(ws + 2212352);
  int*    labels_i = (int*)(ws + 2212864);
  u32*    flag2    = (u32*)(ws + 2229248);

  k_decode <<<1024, 256, 0, stream>>>(pred, out, labels_i, rank_of);
  k_rank   <<<dim3(16, 16), 256, 0, stream>>>(out, rank_of);
  k_scatter<<<16, 256, 0, stream>>>(rank_of, order);
  k_gather <<<16, 256, 0, stream>>>(out, labels_i, order, rbox, rlabel, rvalid);
  k_mat    <<<dim3(2, 256), 256, 0, stream>>>(rbox, rlabel, mat, flag2);
  k_greedy <<<1, 64, 0, stream>>>(mat, rvalid, flag2, keptmask);
  k_final  <<<16, 256, 0, stream>>>(out, rank_of, keptmask);
}

// Round 3
// 64.375 us; speedup vs baseline: 1.4036x; 1.4036x over previous
//
#include <hip/hip_runtime.h>
#include <hip/hip_bf16.h>
#include <math.h>

typedef unsigned long long u64;
typedef unsigned int u32;

#define N 4096
#define NW 64          // 64-bit words per 4096-bit row
#define ROWLEN 85

// ---------------------------------------------------------------------------
// K1: decode — one wave (64 lanes) per prediction row.
//   Also zeroes rank_of (for K2 atomics) and rvalid/flagbits (block 0).
// ---------------------------------------------------------------------------
__global__ __launch_bounds__(256) void k_decode(const float* __restrict__ pred,
    float* __restrict__ out, int* __restrict__ labels_i, int* __restrict__ rank_of,
    u64* __restrict__ rvalid, u64* __restrict__ flagbits) {
  if (blockIdx.x == 0) {
    int t = threadIdx.x;
    if (t < 64) rvalid[t] = 0ull;
    else if (t < 128) flagbits[t - 64] = 0ull;
  }
  int lane = threadIdx.x & 63;
  int r = (blockIdx.x << 2) + (threadIdx.x >> 6);
  const float* p = pred + r * ROWLEN;
  float conf = p[0];
  float c1 = p[1 + lane];
  float c2 = (lane < 16) ? p[65 + lane] : -INFINITY;
  float b0 = p[81], b1 = p[82], b2 = p[83], b3 = p[84];

  float m = fmaxf(c1, c2);
  for (int off = 32; off; off >>= 1) m = fmaxf(m, __shfl_xor(m, off));
  float s = expf(c1 - m) + expf(c2 - m);          // expf(-inf)=0 for lane>=16
  for (int off = 32; off; off >>= 1) s += __shfl_xor(s, off);

  float av = c1; int ai = lane;
  if (c2 > av) { av = c2; ai = 64 + lane; }
  for (int off = 32; off; off >>= 1) {
    float ov = __shfl_xor(av, off); int oi = __shfl_xor(ai, off);
    if (ov > av || (ov == av && oi < ai)) { av = ov; ai = oi; }
  }

  if (lane == 0) {
    float sig = 1.0f / (1.0f + expf(-conf));
    float score = sig * (1.0f / s);               // sig * softmax_max, matches ref op order
    float gx = (float)(r >> 6), gy = (float)(r & 63);
    float cx = (1.0f / (1.0f + expf(-b0)) + gx) * 32.0f;
    float cy = (1.0f / (1.0f + expf(-b1)) + gy) * 32.0f;
    float wx = expf(b2), wy = expf(b3);
    const float inv = 1.0f / 2048.0f;
    float x1 = fminf(fmaxf((cx - wx) * inv, 0.0f), 1.0f);
    float y1 = fminf(fmaxf((cy - wy) * inv, 0.0f), 1.0f);
    float x2 = fminf(fmaxf((cx + wx) * inv, 0.0f), 1.0f);
    float y2 = fminf(fmaxf((cy + wy) * inv, 0.0f), 1.0f);
    out[r*5+0] = x1; out[r*5+1] = y1; out[r*5+2] = x2; out[r*5+3] = y2;
    out[r*5+4] = score;
    out[N*5 + r] = (float)ai;                     // labels output (as float)
    labels_i[r] = ai;
    rank_of[r] = 0;
  }
}

// ---------------------------------------------------------------------------
// K2: stable-descending rank, j-sliced. key = valid ? score : -1 (sentinel).
//   rank_i = #{j : k_j > k_i  or  (k_j == k_i and j < i)}   (== stable argsort)
// ---------------------------------------------------------------------------
__global__ __launch_bounds__(256) void k_rank(const float* __restrict__ out,
                                              int* __restrict__ rank_of) {
  __shared__ float kj[256];
  int i  = (blockIdx.x << 8) + threadIdx.x;
  int j0 = blockIdx.y << 8;
  {
    float sc = out[(j0 + threadIdx.x) * 5 + 4];
    kj[threadIdx.x] = (sc > 0.01f) ? sc : -1.0f;
  }
  __syncthreads();
  float sci = out[i*5+4];
  float ki = (sci > 0.01f) ? sci : -1.0f;
  int rnk = 0;
  #pragma unroll 8
  for (int jj = 0; jj < 256; ++jj) {
    float v = kj[jj];
    rnk += (v > ki || (v == ki && (j0 + jj) < i)) ? 1 : 0;
  }
  if (rnk) atomicAdd(&rank_of[i], rnk);
}

// ---------------------------------------------------------------------------
// K2b: permute (scatter) candidate data into rank order + valid bitmask.
//   Replaces the old scatter+gather pair: thread i owns original index i.
// ---------------------------------------------------------------------------
__global__ __launch_bounds__(256) void k_perm(const float* __restrict__ out,
    const int* __restrict__ labels_i, const int* __restrict__ rank_of,
    float4* __restrict__ rbox, int* __restrict__ rlabel, u64* __restrict__ rvalid) {
  int i = (blockIdx.x << 8) + threadIdx.x;
  int r = rank_of[i];
  float x1 = out[i*5+0], y1 = out[i*5+1], x2 = out[i*5+2], y2 = out[i*5+3];
  float sc = out[i*5+4];
  rbox[r] = make_float4(x1, y1, x2, y2);
  rlabel[r] = labels_i[i];
  if (sc > 0.01f) atomicOr((unsigned long long*)&rvalid[r >> 6], 1ull << (r & 63));
}

// ---------------------------------------------------------------------------
// K3: suppression bit-matrix in rank space (mat[r] bit s: r suppresses s),
//   + packed diagonal-block words (diag[r]) + per-row any-edge bitset
//   (flagbits, bit r&63 of word r>>6). grid (2 s-tiles, 256 row-chunks).
// ---------------------------------------------------------------------------
__global__ __launch_bounds__(256) void k_mat(const float4* __restrict__ rbox,
    const int* __restrict__ rlabel, u64* __restrict__ mat,
    u64* __restrict__ diag, u64* __restrict__ flagbits) {
  __shared__ float4 sbox[2048];
  __shared__ int slab[2048];
  int t = blockIdx.x;                // s-tile 0..1
  int base = t << 11;
  for (int k = threadIdx.x; k < 2048; k += 256) {
    sbox[k] = rbox[base + k];
    slab[k] = rlabel[base + k];
  }
  __syncthreads();
  int lane = threadIdx.x & 63;
  int r0 = (blockIdx.y << 4) + ((threadIdx.x >> 6) << 2);
  for (int q = 0; q < 4; ++q) {
    int r = r0 + q;
    float4 br = rbox[r];
    int lr = rlabel[r];
    float ar = (br.w - br.y) * (br.z - br.x);
    u64 myw = 0; u32 any = 0;
    for (int w = 0; w < 32; ++w) {
      int sl = (w << 6) + lane;
      float4 bs = sbox[sl];
      int ls = slab[sl];
      float as = (bs.w - bs.y) * (bs.z - bs.x);
      float xx1 = fmaxf(br.x, bs.x);
      float yy1 = fmaxf(br.y, bs.y);
      float xx2 = fminf(br.z, bs.z);
      float yy2 = fminf(br.w, bs.w);
      float inter = fmaxf(xx2 - xx1, 0.0f) * fmaxf(yy2 - yy1, 0.0f);
      float uni = ar + as - inter;
      float iou = inter / uni;                     // exact ref formula incl. division
      int sg = base + sl;
      bool sup = (ls == lr) && (iou > 0.5f) && (sg != r);
      u64 bal = __ballot(sup);
      any |= (u32)(bal != 0ull);
      if (lane == w) myw = bal;                    // lane w keeps word w (w<32)
    }
    if (lane < 32) mat[(size_t)r * NW + (t << 5) + lane] = myw;
    int dw = (r >> 6) - (t << 5);                  // diag word idx within this tile
    if (dw >= 0 && dw < 32 && lane == dw) diag[r] = myw;
    if (lane == 0 && any)
      atomicOr((unsigned long long*)&flagbits[r >> 6], 1ull << (r & 63));
  }
}

// ---------------------------------------------------------------------------
// K4: sequential greedy NMS. 256 threads: all stage diag into LDS (coalesced),
//   wave 0 runs the scan. Per-iteration data is LDS (prefetched) + register
//   shfl broadcasts; global mat rows touched only for kept rows with edges.
// ---------------------------------------------------------------------------
__global__ __launch_bounds__(256) void k_greedy(const u64* __restrict__ mat,
    const u64* __restrict__ diag, const u64* __restrict__ rvalid,
    const u64* __restrict__ flagbits, u64* __restrict__ keptmask) {
  __shared__ u64 sdiag[4096];
  int tid = threadIdx.x;
  for (int k = tid; k < 4096; k += 256) sdiag[k] = diag[k];
  __syncthreads();
  if (tid >= 64) return;
  int lane = tid;
  u64 valid = rvalid[lane];
  u64 mflag = flagbits[lane];
  u64 supp = 0, kept = 0;
  u64 intra = sdiag[lane];                         // block b=0 row words
  for (int b = 0; b < 64; ++b) {
    u64 intra_next = (b < 63) ? sdiag[((b + 1) << 6) + lane] : 0ull;
    u64 flagw = __shfl(mflag, b);                  // bit p: row 64b+p has an edge
    u64 sb = __shfl(supp, b);
    u64 vb = __shfl(valid, b);
    u64 act = vb & ~sb;
    u64 res = act;
    u64 anyintra = __ballot(intra != 0ull);
    if (anyintra & act) {                          // rare: serial in-block resolve
      u64 rem = act; res = 0;
      while (rem) {
        int pp = (int)__ffsll(rem) - 1;
        rem &= rem - 1;
        res |= 1ull << pp;
        u64 rowp = __shfl(intra, pp);
        rem &= ~rowp;
      }
    }
    if (lane == b) kept = res;
    u64 need = res & flagw;                        // rare: kept rows with edges
    while (need) {
      int pp = (int)__ffsll(need) - 1;
      need &= need - 1;
      supp |= mat[(size_t)((b << 6) + pp) * NW + lane];
    }
    intra = intra_next;
  }
  keptmask[lane] = kept;
}

// ---------------------------------------------------------------------------
// K5: mask out rows by keep, emit keep section as floats.
// ---------------------------------------------------------------------------
__global__ __launch_bounds__(256) void k_final(float* __restrict__ out,
    const int* __restrict__ rank_of, const u64* __restrict__ keptmask) {
  int i = (blockIdx.x << 8) + threadIdx.x;
  int r = rank_of[i];
  float k = (float)((keptmask[r >> 6] >> (r & 63)) & 1ull);
  out[i*5+0] *= k; out[i*5+1] *= k; out[i*5+2] *= k; out[i*5+3] *= k; out[i*5+4] *= k;
  out[N*5 + N + i] = k;
}

// ---------------------------------------------------------------------------
// ws layout (bytes):
//   0        mat       u64[4096*64]   2097152
//   2097152  rank_of   i32[4096]      16384
//   2113536  rbox      float4[4096]   65536
//   2179072  rlabel    i32[4096]      16384
//   2195456  labels_i  i32[4096]      16384
//   2211840  diag      u64[4096]      32768
//   2244608  rvalid    u64[64]        512
//   2245120  flagbits  u64[64]        512
//   2245632  keptmask  u64[64]        512
//   total 2246144 bytes
// ---------------------------------------------------------------------------
extern "C" void kernel_launch(void* const* d_in, const int* in_sizes, int n_in,
                              void* d_out, int out_size, void* d_ws, size_t ws_size,
                              hipStream_t stream) {
  const float* pred = (const float*)d_in[0];
  float* out = (float*)d_out;
  char* ws = (char*)d_ws;
  u64*    mat      = (u64*)(ws);
  int*    rank_of  = (int*)(ws + 2097152);
  float4* rbox     = (float4*)(ws + 2113536);
  int*    rlabel   = (int*)(ws + 2179072);
  int*    labels_i = (int*)(ws + 2195456);
  u64*    diag     = (u64*)(ws + 2211840);
  u64*    rvalid   = (u64*)(ws + 2244608);
  u64*    flagbits = (u64*)(ws + 2245120);
  u64*    keptmask = (u64*)(ws + 2245632);

  k_decode <<<1024, 256, 0, stream>>>(pred, out, labels_i, rank_of, rvalid, flagbits);
  k_rank   <<<dim3(16, 16), 256, 0, stream>>>(out, rank_of);
  k_perm   <<<16, 256, 0, stream>>>(out, labels_i, rank_of, rbox, rlabel, rvalid);
  k_mat    <<<dim3(2, 256), 256, 0, stream>>>(rbox, rlabel, mat, diag, flagbits);
  k_greedy <<<1, 256, 0, stream>>>(mat, diag, rvalid, flagbits, keptmask);
  k_final  <<<16, 256, 0, stream>>>(out, rank_of, keptmask);
}